// Round 3
// baseline (466.407 us; speedup 1.0000x reference)
//
#include <hip/hip_runtime.h>

// ============================================================================
// RegionNonLocalEnhancedDenseBlock on MI355X (gfx950) — Round 3
//  - qkv_kernel: MFMA Q/K/V gen, in-register 2x2 maxpool, frag-layout outputs.
//  - attn_kernel: 4 blocks/cell, Q/K/V frags straight from global, only P/O
//    LDS round-trips remain. __launch_bounds__(256,4).
//  - conv3x3 / fuse unchanged from round 2 (bf16 MFMA implicit GEMM).
// ============================================================================

typedef short s16x8 __attribute__((ext_vector_type(8)));
typedef float f32x4 __attribute__((ext_vector_type(4)));
typedef unsigned short ushort_t;

__device__ __forceinline__ unsigned short f2bf(float f) {
  union { float f; unsigned int u; } v; v.f = f;
  unsigned int r = v.u + 0x7fffu + ((v.u >> 16) & 1u);  // RNE
  return (unsigned short)(r >> 16);
}

// ---------------------------------------------------------------------------
// Repack conv/fuse weights -> bf16 MFMA B-frag order.
// ---------------------------------------------------------------------------
__global__ void repack_kernel(const float* __restrict__ W1, const float* __restrict__ W2,
                              const float* __restrict__ W3, const float* __restrict__ Wf,
                              ushort_t* __restrict__ wc1, ushort_t* __restrict__ wc2,
                              ushort_t* __restrict__ wc3, ushort_t* __restrict__ wff)
{
  const int i = blockIdx.x * 256 + threadIdx.x;
  if (i < 18432) {  // W1 [32][64][3][3], Kg=8
    int j = i & 7, o = (i >> 3) & 31, r = i >> 8, tap = r >> 3, kg = r & 7;
    wc1[i] = f2bf(W1[o * 576 + (kg * 8 + j) * 9 + tap]);
  }
  if (i < 27648) {  // W2 [32][96][3][3], Kg=12
    int j = i & 7, o = (i >> 3) & 31, r = i >> 8, tap = r / 12, kg = r % 12;
    wc2[i] = f2bf(W2[o * 864 + (kg * 8 + j) * 9 + tap]);
  }
  if (i < 36864) {  // W3 [32][128][3][3], Kg=16
    int j = i & 7, o = (i >> 3) & 31, r = i >> 8, tap = r >> 4, kg = r & 15;
    wc3[i] = f2bf(W3[o * 1152 + (kg * 8 + j) * 9 + tap]);
  }
  if (i < 10240) {  // Wf [64][160], Kg=20
    int j = i & 7, o = (i >> 3) & 63, kg = i >> 9;
    wff[i] = f2bf(Wf[o * 160 + kg * 8 + j]);
  }
}

// ---------------------------------------------------------------------------
// qkv_kernel: grid 2048 (8 blocks/cell, 4 waves each => 32 waves/cell).
// Wave w (0..31) of a cell handles row-pair yp=w>>1, x-half h=w&1:
// two 16-pixel row tiles (y=2yp, 2yp+1). Q stored per tile; K/V maxpooled
// in-register (horizontal: reg pairs, vertical: tile pair) then stored.
// Layouts: qg[cell][qpos][32], kg[cell][kpos][32], vg[cell][32][kpos].
// ---------------------------------------------------------------------------
__global__ __launch_bounds__(256, 4) void qkv_kernel(
    const float* __restrict__ x,
    const float* __restrict__ Wq, const float* __restrict__ bq,
    const float* __restrict__ Wk, const float* __restrict__ bk,
    const float* __restrict__ Wv, const float* __restrict__ bv,
    ushort_t* __restrict__ qg, ushort_t* __restrict__ kg, ushort_t* __restrict__ vg)
{
  const int bid = blockIdx.x;
  const int cell = bid >> 3;
  const int tid = threadIdx.x, lane = tid & 63, wv = tid >> 6;
  const int w = (bid & 7) * 4 + wv;        // 0..31 within cell
  const int yp = w >> 1, h = w & 1;
  const int quad = lane >> 4, l15 = lane & 15;

  const int n  = cell >> 6;
  const int gh = (cell >> 3) & 7;
  const int gw = cell & 7;
  const int y0 = gh * 32, xc0 = gw * 32;
  const float* xn = x + (size_t)n * (64 * 65536);

  // B-frags: W[o][c] -> B[k=c frag][n=o l15]
  s16x8 wqf[2][2], wkf[2][2], wvf[2][2];
#pragma unroll
  for (int ks = 0; ks < 2; ++ks)
#pragma unroll
    for (int nt = 0; nt < 2; ++nt) {
      const int off = (nt * 16 + l15) * 64 + ks * 32 + quad * 8;
      s16x8 tq, tk, tv;
#pragma unroll
      for (int j = 0; j < 8; ++j) {
        tq[j] = (short)f2bf(Wq[off + j]);
        tk[j] = (short)f2bf(Wk[off + j]);
        tv[j] = (short)f2bf(Wv[off + j]);
      }
      wqf[ks][nt] = tq; wkf[ks][nt] = tk; wvf[ks][nt] = tv;
    }
  float bqv[2], bkv[2], bvv[2];
#pragma unroll
  for (int nt = 0; nt < 2; ++nt) {
    bqv[nt] = bq[nt * 16 + l15];
    bkv[nt] = bk[nt * 16 + l15];
    bvv[nt] = bv[nt * 16 + l15];
  }

  const f32x4 zf = {0.f, 0.f, 0.f, 0.f};
  f32x4 kd[2][2], vd[2][2];

#pragma unroll
  for (int t2 = 0; t2 < 2; ++t2) {
    const int yy = 2 * yp + t2;
    const int xx = h * 16 + l15;
    const float* px = xn + (y0 + yy) * 256 + xc0 + xx;

    s16x8 a[2];
#pragma unroll
    for (int ks = 0; ks < 2; ++ks)
#pragma unroll
      for (int j = 0; j < 8; ++j)
        a[ks][j] = (short)f2bf(px[(size_t)(ks * 32 + quad * 8 + j) * 65536]);

#pragma unroll
    for (int nt = 0; nt < 2; ++nt) {
      f32x4 qd = zf;
      kd[t2][nt] = zf; vd[t2][nt] = zf;
#pragma unroll
      for (int ks = 0; ks < 2; ++ks) {
        qd         = __builtin_amdgcn_mfma_f32_16x16x32_bf16(a[ks], wqf[ks][nt], qd, 0, 0, 0);
        kd[t2][nt] = __builtin_amdgcn_mfma_f32_16x16x32_bf16(a[ks], wkf[ks][nt], kd[t2][nt], 0, 0, 0);
        vd[t2][nt] = __builtin_amdgcn_mfma_f32_16x16x32_bf16(a[ks], wvf[ks][nt], vd[t2][nt], 0, 0, 0);
      }
      // Q store: D[row=x-off quad*4+i][col=ch l15]
      ushort_t* qb = qg + ((size_t)(cell << 10) + yy * 32 + h * 16) * 32 + nt * 16 + l15;
#pragma unroll
      for (int i = 0; i < 4; ++i)
        qb[(quad * 4 + i) * 32] = f2bf(qd[i] + bqv[nt]);
    }
  }

  // 2x2 maxpool: horizontal = reg pairs (2r,2r+1), vertical = t2 pair
#pragma unroll
  for (int nt = 0; nt < 2; ++nt) {
#pragma unroll
    for (int r = 0; r < 2; ++r) {
      const float kp = fmaxf(fmaxf(kd[0][nt][2 * r], kd[0][nt][2 * r + 1]),
                             fmaxf(kd[1][nt][2 * r], kd[1][nt][2 * r + 1])) + bkv[nt];
      const float vp = fmaxf(fmaxf(vd[0][nt][2 * r], vd[0][nt][2 * r + 1]),
                             fmaxf(vd[1][nt][2 * r], vd[1][nt][2 * r + 1])) + bvv[nt];
      const int kpos = yp * 16 + h * 8 + quad * 2 + r;
      kg[((size_t)(cell << 8) + kpos) * 32 + nt * 16 + l15] = f2bf(kp);
      vg[(size_t)(cell << 13) + (nt * 16 + l15) * 256 + kpos] = f2bf(vp);
    }
  }
}

// ---------------------------------------------------------------------------
// attn_kernel: grid 1024 (4 blocks/cell), 4 waves, 4 M-tiles per wave.
// Q/K/V fragments loaded straight from global (cached). Only P (C->A) and
// O (C->A) LDS round-trips per wave.
// ---------------------------------------------------------------------------
__global__ __launch_bounds__(256, 4) void attn_kernel(
    const ushort_t* __restrict__ qg, const ushort_t* __restrict__ kg,
    const ushort_t* __restrict__ vg, const float* __restrict__ x,
    const float* __restrict__ Wo, const float* __restrict__ bo,
    const float* __restrict__ gamma_p, ushort_t* __restrict__ f0)
{
  __shared__ __attribute__((aligned(16))) ushort_t pt[4][16 * 136];
  __shared__ __attribute__((aligned(16))) ushort_t ot[4][16 * 40];

  const int bid = blockIdx.x;
  const int cell = bid >> 2;
  const int part = bid & 3;
  const int tid = threadIdx.x, lane = tid & 63, wv = tid >> 6;
  const int quad = lane >> 4, l15 = lane & 15;

  const int n  = cell >> 6;
  const int gh = (cell >> 3) & 7;
  const int gw = cell & 7;
  const int y0 = gh * 32, xc0 = gw * 32;

  const float* xn  = x  + (size_t)n * (64 * 65536);
  ushort_t*    f0n = f0 + (size_t)n * (65536 * 64);
  const ushort_t* qc = qg + (size_t)(cell << 10) * 32;
  const ushort_t* kc = kg + (size_t)(cell << 8) * 32;
  const ushort_t* vc = vg + (size_t)(cell << 13);

  const float gamma = gamma_p[0];

  s16x8 wof[4];
#pragma unroll
  for (int nt = 0; nt < 4; ++nt) {
    const float* p = Wo + (nt * 16 + l15) * 32 + quad * 8;
    s16x8 t;
#pragma unroll
    for (int j = 0; j < 8; ++j) t[j] = (short)f2bf(p[j]);
    wof[nt] = t;
  }
  float bov[4];
#pragma unroll
  for (int nt = 0; nt < 4; ++nt) bov[nt] = bo[nt * 16 + l15];

  ushort_t* ptw = pt[wv];
  ushort_t* otw = ot[wv];
  const f32x4 zf = {0.f, 0.f, 0.f, 0.f};

#pragma unroll 1
  for (int it = 0; it < 4; ++it) {
    const int mt = part * 16 + wv * 4 + it;   // 0..63
    const int pbase = mt * 16;

    // Q A-frag straight from global: [qpos][32]
    const s16x8 qa = *(const s16x8*)(qc + (size_t)(pbase + l15) * 32 + quad * 8);

    // S = Q.K^T, 16 N-tiles; K B-frags from global [kpos][32]
    f32x4 S[16];
#pragma unroll
    for (int nt = 0; nt < 16; ++nt) {
      const s16x8 kb = *(const s16x8*)(kc + (size_t)(nt * 16 + l15) * 32 + quad * 8);
      S[nt] = __builtin_amdgcn_mfma_f32_16x16x32_bf16(qa, kb, zf, 0, 0, 0);
    }

    // softmax over 256 cols (row = quad*4+i, col chunk l15 per tile)
    float rl[4];
#pragma unroll
    for (int i = 0; i < 4; ++i) {
      float m = S[0][i];
#pragma unroll
      for (int nt = 1; nt < 16; ++nt) m = fmaxf(m, S[nt][i]);
#pragma unroll
      for (int d2 = 1; d2 < 16; d2 <<= 1) m = fmaxf(m, __shfl_xor(m, d2, 64));
      float s = 0.f;
#pragma unroll
      for (int nt = 0; nt < 16; ++nt) {
        float e = __expf(S[nt][i] - m);
        S[nt][i] = e;
        s += e;
      }
#pragma unroll
      for (int d2 = 1; d2 < 16; d2 <<= 1) s += __shfl_xor(s, d2, 64);
      rl[i] = s;
    }

    // O = P.V^T over 2 halves of 128 kpos; P via LDS C->A; V B-frags global
    f32x4 O0 = zf, O1 = zf;
#pragma unroll
    for (int hh = 0; hh < 2; ++hh) {
#pragma unroll
      for (int t = 0; t < 8; ++t)
#pragma unroll
        for (int i = 0; i < 4; ++i)
          ptw[(quad * 4 + i) * 136 + t * 16 + l15] = f2bf(S[hh * 8 + t][i]);
#pragma unroll
      for (int kk = 0; kk < 4; ++kk) {
        const s16x8 pa = *(const s16x8*)&ptw[l15 * 136 + kk * 32 + quad * 8];
        const int kb0 = hh * 128 + kk * 32 + quad * 8;
        const s16x8 vb0 = *(const s16x8*)(vc + (size_t)l15 * 256 + kb0);
        const s16x8 vb1 = *(const s16x8*)(vc + (size_t)(16 + l15) * 256 + kb0);
        O0 = __builtin_amdgcn_mfma_f32_16x16x32_bf16(pa, vb0, O0, 0, 0, 0);
        O1 = __builtin_amdgcn_mfma_f32_16x16x32_bf16(pa, vb1, O1, 0, 0, 0);
      }
    }

    // normalize, C->A via LDS, project Wo, epilogue with residual
#pragma unroll
    for (int i = 0; i < 4; ++i) {
      const float inv = 1.0f / rl[i];
      otw[(quad * 4 + i) * 40 + l15]      = f2bf(O0[i] * inv);
      otw[(quad * 4 + i) * 40 + 16 + l15] = f2bf(O1[i] * inv);
    }
    const s16x8 oa = *(const s16x8*)&otw[l15 * 40 + quad * 8];
#pragma unroll
    for (int nt = 0; nt < 4; ++nt) {
      f32x4 D = __builtin_amdgcn_mfma_f32_16x16x32_bf16(oa, wof[nt], zf, 0, 0, 0);
      const int co = nt * 16 + l15;
#pragma unroll
      for (int i = 0; i < 4; ++i) {
        const int p = pbase + quad * 4 + i;
        const int yy = p >> 5, xx = p & 31;
        const int pix = (y0 + yy) * 256 + xc0 + xx;
        const float r = gamma * (D[i] + bov[nt]) + xn[(size_t)co * 65536 + pix];
        f0n[(size_t)pix * 64 + co] = f2bf(r);
      }
    }
  }
}

// ---------------------------------------------------------------------------
// conv3x3 + ReLU via bf16 MFMA implicit GEMM (unchanged from round 2).
// ---------------------------------------------------------------------------
template <int NCHUNK>
__global__ __launch_bounds__(256) void conv3_kernel(
    const ushort_t* __restrict__ s0, const ushort_t* __restrict__ s1,
    const ushort_t* __restrict__ s2, const ushort_t* __restrict__ wc,
    const float* __restrict__ bias, ushort_t* __restrict__ outp)
{
  __shared__ __attribute__((aligned(16))) ushort_t tile[612 * 40];

  const int bid = blockIdx.x;
  const int n = bid >> 7;
  const int t = bid & 127;
  const int ty0 = (t >> 3) * 16;
  const int tx0 = (t & 7) * 32;
  const int tid = threadIdx.x, lane = tid & 63, wv = tid >> 6;
  const int quad = lane >> 4, l15 = lane & 15;
  constexpr int Kg = NCHUNK * 4;

  const f32x4 zf = {0.f, 0.f, 0.f, 0.f};
  f32x4 acc[4][2][2];
#pragma unroll
  for (int r = 0; r < 4; ++r)
#pragma unroll
    for (int h = 0; h < 2; ++h) { acc[r][h][0] = zf; acc[r][h][1] = zf; }

  for (int ch = 0; ch < NCHUNK; ++ch) {
    const ushort_t* src; int cstr, cbase;
    if (ch < 2)       { src = s0 + (size_t)n * (65536 * 64); cstr = 64; cbase = ch * 32; }
    else if (ch == 2) { src = s1 + (size_t)n * (65536 * 32); cstr = 32; cbase = 0; }
    else              { src = s2 + (size_t)n * (65536 * 32); cstr = 32; cbase = 0; }

    __syncthreads();
    for (int u = tid; u < 2448; u += 256) {
      const int pix = u >> 2, cg = u & 3;
      const int lr = pix / 34, lc = pix - lr * 34;
      const int gy = ty0 - 1 + lr, gx = tx0 - 1 + lc;
      s16x8 v = {0, 0, 0, 0, 0, 0, 0, 0};
      if ((unsigned)gy < 256u && (unsigned)gx < 256u)
        v = *(const s16x8*)(src + (size_t)(gy * 256 + gx) * cstr + cbase + cg * 8);
      *(s16x8*)&tile[pix * 40 + cg * 8] = v;
    }
    __syncthreads();

#pragma unroll
    for (int tap = 0; tap < 9; ++tap) {
      const int ky = tap / 3, kx = tap - ky * 3;
      const ushort_t* wb = wc + ((size_t)(tap * Kg + ch * 4 + quad) * 32 + l15) * 8;
      const s16x8 b0 = *(const s16x8*)wb;
      const s16x8 b1 = *(const s16x8*)(wb + 128);
#pragma unroll
      for (int r = 0; r < 4; ++r) {
        const int lr = 4 * wv + r + ky;
#pragma unroll
        for (int h = 0; h < 2; ++h) {
          const int lc = h * 16 + l15 + kx;
          const s16x8 a = *(const s16x8*)&tile[(lr * 34 + lc) * 40 + quad * 8];
          acc[r][h][0] = __builtin_amdgcn_mfma_f32_16x16x32_bf16(a, b0, acc[r][h][0], 0, 0, 0);
          acc[r][h][1] = __builtin_amdgcn_mfma_f32_16x16x32_bf16(a, b1, acc[r][h][1], 0, 0, 0);
        }
      }
    }
  }

  const float bv0 = bias[l15], bv1 = bias[16 + l15];
  ushort_t* on = outp + (size_t)n * (65536 * 32);
#pragma unroll
  for (int r = 0; r < 4; ++r) {
    const int gy = ty0 + 4 * wv + r;
#pragma unroll
    for (int h = 0; h < 2; ++h) {
#pragma unroll
      for (int i = 0; i < 4; ++i) {
        const int gx = tx0 + h * 16 + quad * 4 + i;
        ushort_t* op = on + (size_t)(gy * 256 + gx) * 32;
        op[l15]      = f2bf(fmaxf(acc[r][h][0][i] + bv0, 0.f));
        op[16 + l15] = f2bf(fmaxf(acc[r][h][1][i] + bv1, 0.f));
      }
    }
  }
}

// ---------------------------------------------------------------------------
// fuse: out = cat(f0..f3)[160] x Wf^T + bf + x (unchanged from round 2).
// ---------------------------------------------------------------------------
__global__ __launch_bounds__(256) void fuse_kernel(
    const ushort_t* __restrict__ f0, const ushort_t* __restrict__ f1,
    const ushort_t* __restrict__ f2, const ushort_t* __restrict__ f3,
    const float* __restrict__ x, const ushort_t* __restrict__ wff,
    const float* __restrict__ bfv, float* __restrict__ out)
{
  __shared__ float tr[4][64 * 17];

  const int tid = threadIdx.x, lane = tid & 63, wv = tid >> 6;
  const int quad = lane >> 4, l15 = lane & 15;

  s16x8 wf[5][4];
#pragma unroll
  for (int ks = 0; ks < 5; ++ks)
#pragma unroll
    for (int nt = 0; nt < 4; ++nt)
      wf[ks][nt] = *(const s16x8*)(wff + ((size_t)((ks * 4 + quad) * 64) + nt * 16 + l15) * 8);
  float bb[4];
#pragma unroll
  for (int nt = 0; nt < 4; ++nt) bb[nt] = bfv[nt * 16 + l15];

  const int wt = blockIdx.x * 4 + wv;
  const f32x4 zf = {0.f, 0.f, 0.f, 0.f};
  float* trw = tr[wv];

  for (int mt = 0; mt < 4; ++mt) {
    const int p0 = wt * 64 + mt * 16;
    const size_t pA = (size_t)(p0 + l15);
    const s16x8 a0 = *(const s16x8*)(f0 + pA * 64 + quad * 8);
    const s16x8 a1 = *(const s16x8*)(f0 + pA * 64 + 32 + quad * 8);
    const s16x8 a2 = *(const s16x8*)(f1 + pA * 32 + quad * 8);
    const s16x8 a3 = *(const s16x8*)(f2 + pA * 32 + quad * 8);
    const s16x8 a4 = *(const s16x8*)(f3 + pA * 32 + quad * 8);

    f32x4 acc[4];
#pragma unroll
    for (int nt = 0; nt < 4; ++nt) {
      f32x4 d = zf;
      d = __builtin_amdgcn_mfma_f32_16x16x32_bf16(a0, wf[0][nt], d, 0, 0, 0);
      d = __builtin_amdgcn_mfma_f32_16x16x32_bf16(a1, wf[1][nt], d, 0, 0, 0);
      d = __builtin_amdgcn_mfma_f32_16x16x32_bf16(a2, wf[2][nt], d, 0, 0, 0);
      d = __builtin_amdgcn_mfma_f32_16x16x32_bf16(a3, wf[3][nt], d, 0, 0, 0);
      d = __builtin_amdgcn_mfma_f32_16x16x32_bf16(a4, wf[4][nt], d, 0, 0, 0);
      acc[nt] = d;
    }

#pragma unroll
    for (int nt = 0; nt < 4; ++nt)
#pragma unroll
      for (int i = 0; i < 4; ++i)
        trw[(nt * 16 + l15) * 17 + quad * 4 + i] = acc[nt][i] + bb[nt];

    const int n = p0 >> 16;
    const int pix0 = p0 & 65535;
    const float* xb = x + (size_t)n * (64 * 65536);
    float* ob = out + (size_t)n * (64 * 65536);
#pragma unroll
    for (int og = 0; og < 16; ++og) {
      const int o = og * 4 + quad;
      const float v = trw[o * 17 + l15];
      const size_t g = (size_t)o * 65536 + pix0 + l15;
      ob[g] = v + xb[g];
    }
  }
}

// ---------------------------------------------------------------------------
extern "C" void kernel_launch(void* const* d_in, const int* in_sizes, int n_in,
                              void* d_out, int out_size, void* d_ws, size_t ws_size,
                              hipStream_t stream)
{
  const float* x     = (const float*)d_in[0];
  const float* Wq    = (const float*)d_in[1];
  const float* bq    = (const float*)d_in[2];
  const float* Wk    = (const float*)d_in[3];
  const float* bk    = (const float*)d_in[4];
  const float* Wv    = (const float*)d_in[5];
  const float* bv    = (const float*)d_in[6];
  const float* Wo    = (const float*)d_in[7];
  const float* bo    = (const float*)d_in[8];
  const float* gamma = (const float*)d_in[9];
  const float* W1    = (const float*)d_in[10];
  const float* b1    = (const float*)d_in[11];
  const float* W2    = (const float*)d_in[12];
  const float* b2    = (const float*)d_in[13];
  const float* W3    = (const float*)d_in[14];
  const float* b3    = (const float*)d_in[15];
  const float* Wf    = (const float*)d_in[16];
  const float* bf    = (const float*)d_in[17];

  float* out = (float*)d_out;
  ushort_t* wsu = (ushort_t*)d_ws;

  // bf16 feature buffers, pixel-major [n][y][x][c]
  ushort_t* f0 = wsu;                       // 16777216
  ushort_t* f1 = wsu + 16777216;            //  8388608
  ushort_t* f2 = wsu + 25165824;            //  8388608
  ushort_t* f3 = wsu + 33554432;            //  8388608
  // qg overlays f1 slot (dead before conv1 writes f1);
  // kg/vg overlay f2 slot (dead before conv2 writes f2)
  ushort_t* qg = wsu + 16777216;            //  8388608 = 262144 pos x 32
  ushort_t* kg = wsu + 25165824;            //  2097152 = 65536 kpos x 32
  ushort_t* vg = wsu + 27262976;            //  2097152
  ushort_t* wc1 = wsu + 41943040;           // 18432
  ushort_t* wc2 = wc1 + 18432;              // 27648
  ushort_t* wc3 = wc2 + 27648;              // 36864
  ushort_t* wff = wc3 + 36864;              // 10240

  repack_kernel<<<144, 256, 0, stream>>>(W1, W2, W3, Wf, wc1, wc2, wc3, wff);
  qkv_kernel<<<2048, 256, 0, stream>>>(x, Wq, bq, Wk, bk, Wv, bv, qg, kg, vg);
  attn_kernel<<<1024, 256, 0, stream>>>(qg, kg, vg, x, Wo, bo, gamma, f0);
  conv3_kernel<2><<<512, 256, 0, stream>>>(f0, f1, f2, wc1, b1, f1);
  conv3_kernel<3><<<512, 256, 0, stream>>>(f0, f1, f2, wc2, b2, f2);
  conv3_kernel<4><<<512, 256, 0, stream>>>(f0, f1, f2, wc3, b3, f3);
  fuse_kernel<<<1024, 256, 0, stream>>>(f0, f1, f2, f3, x, wff, bf, out);
}